// Round 13
// baseline (225.394 us; speedup 1.0000x reference)
//
#include <hip/hip_runtime.h>

#define SIZE_U 1000
#define SIZE_V 1000
#define DIM    128
#define M_EXTRA 16

typedef float f32x4 __attribute__((ext_vector_type(4)));

// Output flat layout (f32 elements):
//   outputs : [0, 2e6)            (1e6 x 2)
//   lnc_rep : [2e6, 130e6)        (1e6 x 128)
//   dis_rep : [130e6, 258e6)      (1e6 x 128)
//   M       : [258e6, 258e6+2048) (16 x 128)
#define OUT_LNC_OFF 2000000L
#define OUT_DIS_OFF 130000000L
#define OUT_M_OFF   258000000L

// R13 = R12 + fine-grained copy chunks to kill the dispatch tail.
// Copy block cost was ~19us (512KB); demand-dispatch leaves a ~10-19us ragged
// tail (the constant across R4-R12's 191-195us plateau). Now: 16000 copy
// chunks of 125 rows = 64KB CONTIGUOUS each (~2.5us) -> tail ~2-3us.
// (R10's regression was its dis chunks scattering 4KB stores across 50
// panels, not chunk size; every chunk here is one contiguous stream.)
// 18001 blocks, groups of 9 = {4 lnc, 4 dis, 1 score}; gcd(9,8)=1 -> no
// role<->XCD aliasing; roles temporally mixed throughout (R5 lesson).
//   g=b/9, k=b%9:
//     k in [0,4) : lnc chunk id=g*4+k   in [0,8000): u=id>>3, rows [(id&7)*125,+125)
//     k in [4,8) : dis chunk id=g*4+k-4 in [0,8000): same row mapping
//     k == 8     : score chunk id=g in [0,2000): u=id>>1, rows [(id&1)*500,+500)
//                  (R12 score block: shuffle-reduce -> LDS -> 4KB burst store)
//   b == 18000 : M copy
__global__ __launch_bounds__(256) void bilinear_v13_kernel(
    const float* __restrict__ feature,
    const float* __restrict__ weight,
    const float* __restrict__ wc,
    float* __restrict__ out)
{
    const int b = blockIdx.x;
    const int t = threadIdx.x;

    if (b == 18000) {
        const f32x4* src = (const f32x4*)(feature + (size_t)(SIZE_U + SIZE_V) * DIM);
        f32x4* dst = (f32x4*)(out + OUT_M_OFF);
        for (int i = t; i < (M_EXTRA * DIM) / 4; i += 256) dst[i] = src[i];
        return;
    }

    const int g = b / 9;
    const int k = b % 9;
    const int c  = t & 31;   // float4 column 0..31
    const int rg = t >> 5;   // row group 0..7
    const f32x4* dis4 = (const f32x4*)(feature + (size_t)SIZE_U * DIM);

    if (k < 8) {
        // ---- copy chunk: 125 contiguous rows of one stream of one u ----
        const int id = g * 4 + (k & 3);
        const int u  = id >> 3;
        const int r0 = (id & 7) * 125;
        const int r1 = r0 + 125;
        const size_t rowbase = (size_t)u * SIZE_V;

        if (k < 4) {
            // pure lnc_rep broadcast: zero loads in loop
            const f32x4 lnc4 = ((const f32x4*)(feature + (size_t)u * DIM))[c];
            f32x4* lr = (f32x4*)(out + OUT_LNC_OFF) + rowbase * (DIM / 4);
            #pragma unroll 8
            for (int r = r0 + rg; r < r1; r += 8)
                lr[r * 32 + c] = lnc4;
        } else {
            // dis_rep: load-once -> store, contiguous 64KB
            f32x4* dr = (f32x4*)(out + OUT_DIS_OFF) + rowbase * (DIM / 4);
            #pragma unroll 8
            for (int r = r0 + rg; r < r1; r += 8) {
                const int idx = r * 32 + c;
                dr[idx] = dis4[idx];
            }
        }
        return;
    }

    // ---- score chunk: u = g>>1, rows [(g&1)*500, +500) ----
    const int u  = g >> 1;
    const int r0 = (g & 1) * 500;
    const int r1 = r0 + 500;

    __shared__ float lnc_s[DIM];
    __shared__ float proj_s[2][DIM];
    __shared__ float q_s[2][DIM];
    __shared__ float2 res_s[500];   // 4 KB staging for full-line burst

    if (t < DIM) lnc_s[t] = feature[(size_t)u * DIM + t];
    __syncthreads();

    {   // proj[kk][e] = sum_d weight[kk][d][e] * lnc[d]
        const int kk = t >> 7, e = t & 127;
        const float* wk = weight + (size_t)kk * DIM * DIM + e;
        float acc = 0.f;
        #pragma unroll 8
        for (int d = 0; d < DIM; ++d)
            acc = fmaf(wk[(size_t)d * DIM], lnc_s[d], acc);
        proj_s[kk][e] = acc;
    }
    __syncthreads();

    {   // fold classifier: q[cc][e] = wc[0][cc]*proj0[e] + wc[2+cc]*proj1[e]
        const int cc = t >> 7, e = t & 127;
        q_s[cc][e] = wc[cc] * proj_s[0][e] + wc[2 + cc] * proj_s[1][e];
    }
    __syncthreads();

    const f32x4 q0 = ((const f32x4*)q_s[0])[c];
    const f32x4 q1 = ((const f32x4*)q_s[1])[c];

    #pragma unroll 4
    for (int r = r0 + rg; r < r1; r += 8) {
        const f32x4 dv = dis4[r * 32 + c];
        float t0 = dv.x * q0.x + dv.y * q0.y + dv.z * q0.z + dv.w * q0.w;
        float t1 = dv.x * q1.x + dv.y * q1.y + dv.z * q1.z + dv.w * q1.w;
        #pragma unroll
        for (int off = 16; off; off >>= 1) {
            t0 += __shfl_xor(t0, off);
            t1 += __shfl_xor(t1, off);
        }
        if (c == 0)
            res_s[r - r0] = make_float2(t0 > 0.f ? t0 : 0.f,
                                        t1 > 0.f ? t1 : 0.f);
    }
    __syncthreads();

    // burst: 500 float2 = 250 f32x4, contiguous + aligned (full lines)
    f32x4* ob = (f32x4*)(out + (size_t)u * (2 * SIZE_V) + (size_t)r0 * 2);
    if (t < 250) ob[t] = ((const f32x4*)res_s)[t];
}

extern "C" void kernel_launch(void* const* d_in, const int* in_sizes, int n_in,
                              void* d_out, int out_size, void* d_ws, size_t ws_size,
                              hipStream_t stream) {
    const float* feature = (const float*)d_in[0];
    const float* weight  = (const float*)d_in[1];
    const float* wc      = (const float*)d_in[2];
    float* out = (float*)d_out;

    bilinear_v13_kernel<<<18001, 256, 0, stream>>>(feature, weight, wc, out);
}

// Round 14
// 192.836 us; speedup vs baseline: 1.1688x; 1.1688x over previous
//
#include <hip/hip_runtime.h>

#define SIZE_U 1000
#define SIZE_V 1000
#define DIM    128
#define M_EXTRA 16

typedef float f32x4 __attribute__((ext_vector_type(4)));

// Output flat layout (f32 elements):
//   outputs : [0, 2e6)            (1e6 x 2)
//   lnc_rep : [2e6, 130e6)        (1e6 x 128)
//   dis_rep : [130e6, 258e6)      (1e6 x 128)
//   M       : [258e6, 258e6+2048) (16 x 128)
#define OUT_LNC_OFF 2000000L
#define OUT_DIS_OFF 130000000L
#define OUT_M_OFF   258000000L

// R14 = R12 verbatim (proven best: 191.1us). Final configuration:
//  - 4001 blocks, roles interleaved in groups of 8 (temporal mixing + XCD
//    parity; contiguous role ranges serialize -> 240us, R5)
//  - copy blocks own 512KB of contiguous store streams (finer chunks pay
//    per-block store-drain + prologue: 64KB chunks -> 225us, R13; scattered
//    4KB stores -> 231us, R10)
//  - plain write-allocate stores (NT stores -> +8us, R6 A/B)
//  - score blocks are pure compute + LDS-staged full-line output burst
//    (8-byte lane0 stores caused partial-line RMW: +3us, R12 A/B;
//    store-in-score-loop chains 512MB behind shuffle latency -> 273us, R7)
//  - work-stealing atomics+barriers -> 269us (R9); score-first phases -> 232us
//    (R11); residency displacement was a dead end (R8 unroll-4: neutral)
//   g = b>>3; role = g&1; j = (g>>1)*8 + (b&7) in [0,2000)
//   u = j>>1; half = j&1 -> rows [half*500, half*500+500)
//   b == 4000 : M copy
__global__ __launch_bounds__(256) void bilinear_v14_kernel(
    const float* __restrict__ feature,
    const float* __restrict__ weight,
    const float* __restrict__ wc,
    float* __restrict__ out)
{
    const int b = blockIdx.x;
    const int t = threadIdx.x;

    if (b == 4000) {
        const f32x4* src = (const f32x4*)(feature + (size_t)(SIZE_U + SIZE_V) * DIM);
        f32x4* dst = (f32x4*)(out + OUT_M_OFF);
        for (int i = t; i < (M_EXTRA * DIM) / 4; i += 256) dst[i] = src[i];
        return;
    }

    const int g    = b >> 3;
    const int role = g & 1;
    const int j    = (g >> 1) * 8 + (b & 7);
    const int u    = j >> 1;
    const int r0   = (j & 1) * 500;
    const int r1   = r0 + 500;

    const int c  = t & 31;   // float4 column 0..31
    const int rg = t >> 5;   // row group 0..7
    const f32x4* dis4 = (const f32x4*)(feature + (size_t)SIZE_U * DIM);
    const size_t rowbase = (size_t)u * SIZE_V;

    if (role == 0) {
        // ---- phase 1: pure lnc_rep streaming (zero loads) ----
        const f32x4 lnc4 = ((const f32x4*)(feature + (size_t)u * DIM))[c];
        f32x4* lr = (f32x4*)(out + OUT_LNC_OFF) + rowbase * (DIM / 4);
        #pragma unroll 8
        for (int r = r0 + rg; r < r1; r += 8)
            lr[r * 32 + c] = lnc4;

        // ---- phase 2: dis -> dis_rep (load + store, deep unroll) ----
        f32x4* dr = (f32x4*)(out + OUT_DIS_OFF) + rowbase * (DIM / 4);
        #pragma unroll 8
        for (int r = r0 + rg; r < r1; r += 8) {
            const int idx = r * 32 + c;
            dr[idx] = dis4[idx];
        }
    } else {
        // ---- score block ----
        __shared__ float lnc_s[DIM];
        __shared__ float proj_s[2][DIM];
        __shared__ float q_s[2][DIM];
        __shared__ float2 res_s[500];   // 4 KB staging for full-line burst

        if (t < DIM) lnc_s[t] = feature[(size_t)u * DIM + t];
        __syncthreads();

        {   // proj[k][e] = sum_d weight[k][d][e] * lnc[d]
            const int k = t >> 7, e = t & 127;
            const float* wk = weight + (size_t)k * DIM * DIM + e;
            float acc = 0.f;
            #pragma unroll 8
            for (int d = 0; d < DIM; ++d)
                acc = fmaf(wk[(size_t)d * DIM], lnc_s[d], acc);
            proj_s[k][e] = acc;
        }
        __syncthreads();

        {   // fold classifier: q[cc][e] = wc[0][cc]*proj0[e] + wc[2+cc]*proj1[e]
            const int cc = t >> 7, e = t & 127;
            q_s[cc][e] = wc[cc] * proj_s[0][e] + wc[2 + cc] * proj_s[1][e];
        }
        __syncthreads();

        const f32x4 q0 = ((const f32x4*)q_s[0])[c];
        const f32x4 q1 = ((const f32x4*)q_s[1])[c];

        #pragma unroll 4
        for (int r = r0 + rg; r < r1; r += 8) {
            const f32x4 dv = dis4[r * 32 + c];
            float t0 = dv.x * q0.x + dv.y * q0.y + dv.z * q0.z + dv.w * q0.w;
            float t1 = dv.x * q1.x + dv.y * q1.y + dv.z * q1.z + dv.w * q1.w;
            #pragma unroll
            for (int off = 16; off; off >>= 1) {
                t0 += __shfl_xor(t0, off);
                t1 += __shfl_xor(t1, off);
            }
            if (c == 0)
                res_s[r - r0] = make_float2(t0 > 0.f ? t0 : 0.f,
                                            t1 > 0.f ? t1 : 0.f);
        }
        __syncthreads();

        // burst: 500 float2 = 250 f32x4, contiguous + aligned (full lines)
        f32x4* ob = (f32x4*)(out + (size_t)u * (2 * SIZE_V) + (size_t)r0 * 2);
        if (t < 250) ob[t] = ((const f32x4*)res_s)[t];
    }
}

extern "C" void kernel_launch(void* const* d_in, const int* in_sizes, int n_in,
                              void* d_out, int out_size, void* d_ws, size_t ws_size,
                              hipStream_t stream) {
    const float* feature = (const float*)d_in[0];
    const float* weight  = (const float*)d_in[1];
    const float* wc      = (const float*)d_in[2];
    float* out = (float*)d_out;

    bilinear_v14_kernel<<<4001, 256, 0, stream>>>(feature, weight, wc, out);
}